// Round 5
// baseline (377.942 us; speedup 1.0000x reference)
//
#include <hip/hip_runtime.h>
#include <hip/hip_cooperative_groups.h>

namespace cg = cooperative_groups;

// GaussianMRIModel: splat 25000 anisotropic 3D Gaussians into 160^3 x 2 fp32.
// R4: ONE cooperative kernel (harness dispatch gaps measured ~22 us each):
//   phase0 zero counts | grid.sync | phase1 prep+bin | grid.sync | phase2 gather
// Gather: wave-per-tile, per-wave LDS staging of 16 param structs per batch
// (R2-proven; removes R3's serial scalar-load chain). Packed bounds are
// readfirstlane'd so z/y/x masking runs on SALU; y/x reject folds into
// r0m/r1m cndmasks (no branch). z-column exp recurrence:
//   w(z+1)=w(z)*u(z), u(z+1)=u(z)*v, v=2^(2*q00) per-gaussian const.

namespace {
constexpr int GD = 160, GH = 160, GW = 160;
constexpr int NPTS = 25000;
constexpr int PATCH = 20;
constexpr int TS  = 8;               // tile edge
constexpr int TPD = GD / TS;         // 20
constexpr int NT  = TPD * TPD * TPD; // 8000 tiles
constexpr int CAP = 384;             // per-tile bucket capacity (mean ~81)
constexpr int PSTRIDE = 16;          // floats per gaussian struct
constexpr float L2E = 1.4426950408889634f;
}

// Param struct (16 floats, 4x float4), coefficients pre-scaled by log2(e),
// -0.5 folded; gather computes t in exp2 space directly:
//  P0 = (q00, q01, q02, q11)
//  P1 = (q12, q22, cvz, cvy)
//  P2 = (cvx, r0, r1, loPack)  loPack = loz|loy<<8|lox<<16|upz<<24
//  P3 = (upPack, v, 0, 0)      upPack = upy|upx<<8 ; v = 2^(2*q00) = e^-p00

__global__ __launch_bounds__(256, 8) void fused(
    const float* __restrict__ centers,
    const float* __restrict__ log_scales,
    const float* __restrict__ quats,
    const float* __restrict__ rho,
    float* __restrict__ params,
    int* __restrict__ counts,
    unsigned short* __restrict__ list,
    float2* __restrict__ out)
{
    cg::grid_group grid = cg::this_grid();
    const int nthreads = (int)gridDim.x * 256;
    const int tid = blockIdx.x * 256 + threadIdx.x;

    // ---------------- phase 0: zero tile counts ----------------
    for (int i = tid; i < NT; i += nthreads) counts[i] = 0;
    grid.sync();

    // ---------------- phase 1: per-gaussian prep + bin ----------------
    for (int gid = tid; gid < NPTS; gid += nthreads) {
        const float r0 = rho[gid * 2 + 0];
        const float r1 = rho[gid * 2 + 1];
        const float s0 = __expf(log_scales[gid * 3 + 0]);
        const float s1 = __expf(log_scales[gid * 3 + 1]);
        const float s2 = __expf(log_scales[gid * 3 + 2]);

        const float smax = fmaxf(s0, fmaxf(s1, s2));
        const float rad  = smax * 3.0f;          // RADIUS_FACTOR
        const float amp2 = r0 * r0 + r1 * r1;

        const float cvz = centers[gid * 3 + 0] * (float)(GD - 1);
        const float cvy = centers[gid * 3 + 1] * (float)(GH - 1);
        const float cvx = centers[gid * 3 + 2] * (float)(GW - 1);

        const int bz = (int)floorf(cvz - rad);
        const int by = (int)floorf(cvy - rad);
        const int bx = (int)floorf(cvx - rad);
        const int hz = (int)ceilf(cvz + rad);
        const int hy = (int)ceilf(cvy + rad);
        const int hx = (int)ceilf(cvx + rad);

        // reference mask: idx>=0 && idx<dim && idx<=hi, idx in [base, base+19]
        const int loz = max(bz, 0), upz = min(min(hz, GD - 1), bz + PATCH - 1);
        const int loy = max(by, 0), upy = min(min(hy, GH - 1), by + PATCH - 1);
        const int lox = max(bx, 0), upx = min(min(hx, GW - 1), bx + PATCH - 1);

        const bool valid = (amp2 >= 1e-12f) && (rad >= 1e-3f) &&
                           (upz >= loz) && (upy >= loy) && (upx >= lox);

        const float q0 = quats[gid * 4 + 0], q1 = quats[gid * 4 + 1];
        const float q2 = quats[gid * 4 + 2], q3 = quats[gid * 4 + 3];
        float qn = sqrtf(q0 * q0 + q1 * q1 + q2 * q2 + q3 * q3);
        qn = fmaxf(qn, 1e-6f);
        const float w = q0 / qn, x = q1 / qn, y = q2 / qn, z = q3 / qn;

        const float R00 = w * w + x * x - y * y - z * z;
        const float R01 = 2.f * (x * y - w * z);
        const float R02 = 2.f * (x * z + w * y);
        const float R10 = 2.f * (x * y + w * z);
        const float R11 = w * w - x * x + y * y - z * z;
        const float R12 = 2.f * (y * z - w * x);
        const float R20 = 2.f * (x * z - w * y);
        const float R21 = 2.f * (y * z + w * x);
        const float R22 = w * w - x * x - y * y + z * z;

        const float c0 = fmaxf(s0, 1e-4f); const float i0 = 1.f / (c0 * c0);
        const float c1 = fmaxf(s1, 1e-4f); const float i1 = 1.f / (c1 * c1);
        const float c2 = fmaxf(s2, 1e-4f); const float i2 = 1.f / (c2 * c2);

        const float p00 = R00 * R00 * i0 + R01 * R01 * i1 + R02 * R02 * i2;
        const float p01 = R00 * R10 * i0 + R01 * R11 * i1 + R02 * R12 * i2;
        const float p02 = R00 * R20 * i0 + R01 * R21 * i1 + R02 * R22 * i2;
        const float p11 = R10 * R10 * i0 + R11 * R11 * i1 + R12 * R12 * i2;
        const float p12 = R10 * R20 * i0 + R11 * R21 * i1 + R12 * R22 * i2;
        const float p22 = R20 * R20 * i0 + R21 * R21 * i1 + R22 * R22 * i2;

        const float q00s = -0.5f * L2E * p00;
        const float v    = __builtin_amdgcn_exp2f(2.f * q00s);  // e^-p00

        const int zl = valid ? loz : 255, zu = valid ? upz : 0;
        const int yl = valid ? loy : 255, yu = valid ? upy : 0;
        const int xl = valid ? lox : 255, xu = valid ? upx : 0;
        const int loPack = zl | (yl << 8) | (xl << 16) | (zu << 24);
        const int upPack = yu | (xu << 8);

        float4* P = reinterpret_cast<float4*>(params + (size_t)gid * PSTRIDE);
        P[0] = make_float4(q00s, -L2E * p01, -L2E * p02, -0.5f * L2E * p11);
        P[1] = make_float4(-L2E * p12, -0.5f * L2E * p22, cvz, cvy);
        P[2] = make_float4(cvx, r0, r1, __int_as_float(loPack));
        P[3] = make_float4(__int_as_float(upPack), v, 0.f, 0.f);

        if (valid) {
            const int tz0 = loz >> 3, tz1 = upz >> 3;
            const int ty0 = loy >> 3, ty1 = upy >> 3;
            const int tx0 = lox >> 3, tx1 = upx >> 3;
            for (int tz = tz0; tz <= tz1; ++tz)
                for (int ty = ty0; ty <= ty1; ++ty)
                    for (int tx = tx0; tx <= tx1; ++tx) {
                        const int t = (tz * TPD + ty) * TPD + tx;
                        const int pos = atomicAdd(&counts[t], 1);
                        if (pos < CAP)
                            list[(size_t)t * CAP + pos] = (unsigned short)gid;
                    }
        }
    }
    grid.sync();

    // ---------------- phase 2: gather, one wave per tile ----------------
    const int wli  = threadIdx.x >> 6;
    const int lane = threadIdx.x & 63;
    const int ly = lane >> 3, lx = lane & 7;
    const int totalWaves = nthreads >> 6;
    __shared__ float4 sP[4][16][4];   // [wave][slot][word] = 4 KB
    const float4* p4 = reinterpret_cast<const float4*>(params);

    for (int tile = blockIdx.x * 4 + wli; tile < NT; tile += totalWaves) {
        const int tz = tile / (TPD * TPD);
        const int rem = tile - tz * (TPD * TPD);
        const int ty = rem / TPD;
        const int tx = rem - ty * TPD;
        const int iy = ty * TS + ly;
        const int ix = tx * TS + lx;
        const int z0 = tz * TS;
        const float fy = (float)iy, fx = (float)ix, fz = (float)z0;

        int cnt = __builtin_amdgcn_readfirstlane(counts[tile]);
        if (cnt > CAP) cnt = CAP;
        const unsigned short* tl = list + (size_t)tile * CAP;

        float ar[8], ai[8];
#pragma unroll
        for (int i = 0; i < 8; ++i) { ar[i] = 0.f; ai[i] = 0.f; }

        for (int b0 = 0; b0 < cnt; b0 += 16) {
            const int nb = min(16, cnt - b0);
            const int slot = lane >> 2, word = lane & 3;
            if (slot < nb) {
                const int g = tl[b0 + slot];
                sP[wli][slot][word] = p4[(size_t)g * 4 + word];
            }
            // same-wave ds_write -> ds_read: compiler-inserted lgkmcnt suffices
            for (int g = 0; g < nb; ++g) {
                const float4 Pa = sP[wli][g][0];
                const float4 Pb = sP[wli][g][1];
                const float4 Pc = sP[wli][g][2];
                const float2 Pd = *reinterpret_cast<const float2*>(&sP[wli][g][3]);
                const int lo = __builtin_amdgcn_readfirstlane(__float_as_int(Pc.w));
                const int up = __builtin_amdgcn_readfirstlane(__float_as_int(Pd.x));
                const int loy_ = (lo >> 8) & 255, lox_ = (lo >> 16) & 255;
                const int upy_ = up & 255,        upx_ = (up >> 8) & 255;
                const int zl = (lo & 255) - z0;          // scalar, may be <0 or >7
                const int zu = ((lo >> 24) & 255) - z0;
                const bool yx = (iy >= loy_) & (iy <= upy_) &
                                (ix >= lox_) & (ix <= upx_);

                const float dy = fy - Pb.w;
                const float dx = fx - Pc.x;
                const float C = fmaf(dy, fmaf(Pa.w, dy, Pb.x * dx), Pb.y * dx * dx);
                const float B = fmaf(Pa.y, dy, Pa.z * dx);
                const float dz = fz - Pb.z;
                const float t0 = fmaf(dz, fmaf(Pa.x, dz, B), C);
                const float dt = fmaf(Pa.x, fmaf(2.f, dz, 1.f), B);
                float wgt = __builtin_amdgcn_exp2f(t0);  // weight at z0 (<=1)
                float u   = __builtin_amdgcn_exp2f(dt);  // ratio at z0
                const float v = Pd.y;                    // ratio of ratios
                const float r0m = yx ? Pc.y : 0.f;       // fold y/x reject
                const float r1m = yx ? Pc.z : 0.f;
#pragma unroll
                for (int i = 0; i < 8; ++i) {
                    const float wm = (i >= zl && i <= zu) ? wgt : 0.f;
                    ar[i] = fmaf(wm, r0m, ar[i]);
                    ai[i] = fmaf(wm, r1m, ai[i]);
                    wgt *= u;
                    u *= v;
                }
            }
        }

#pragma unroll
        for (int i = 0; i < 8; ++i)
            out[((size_t)(z0 + i) * GH + iy) * GW + ix] = make_float2(ar[i], ai[i]);
    }
}

extern "C" void kernel_launch(void* const* d_in, const int* in_sizes, int n_in,
                              void* d_out, int out_size, void* d_ws, size_t ws_size,
                              hipStream_t stream) {
    const float* centers    = (const float*)d_in[0];
    const float* log_scales = (const float*)d_in[1];
    const float* quats      = (const float*)d_in[2];
    const float* rho        = (const float*)d_in[3];

    // workspace: params (1.6 MB) | counts (32 KB) | list (6.1 MB)
    float* params = (float*)d_ws;
    int* counts = (int*)(params + (size_t)NPTS * PSTRIDE);
    unsigned short* list = (unsigned short*)(counts + NT);
    float2* out = (float2*)d_out;

    int maxb = 4;   // safe fallback if the query fails
    (void)hipOccupancyMaxActiveBlocksPerMultiprocessor(&maxb, fused, 256, 0);
    if (maxb < 1) maxb = 1;
    int nblk = maxb * 256;            // 256 CUs
    if (nblk > NT / 4) nblk = NT / 4; // 2000 blocks = 1 tile per wave

    void* args[] = {(void*)&centers, (void*)&log_scales, (void*)&quats,
                    (void*)&rho, (void*)&params, (void*)&counts,
                    (void*)&list, (void*)&out};
    hipLaunchCooperativeKernel((const void*)fused, dim3(nblk), dim3(256),
                               args, 0, stream);
}

// Round 6
// 174.155 us; speedup vs baseline: 2.1702x; 2.1702x over previous
//
#include <hip/hip_runtime.h>

// GaussianMRIModel: splat 25000 anisotropic 3D Gaussians into 160^3 x 2 fp32.
// R5: revert cooperative experiment (grid.sync cost ~100+us each on 8 XCDs).
// Proven 3-dispatch structure: memset | prep_bin | gather.
// Gather: 256-thr blocks = 4 INDEPENDENT waves, one tile per wave, per-wave
// batch-64 LDS staging (R2's latency amortization, R4's conflict-free per-wave
// form, no barriers). Wave-uniform packed bounds readfirstlane'd -> masking on
// SALU pipe. z-column exp recurrence: w*=u, u*=v, v=2^(2*q00) const.

namespace {
constexpr int GD = 160, GH = 160, GW = 160;
constexpr int NPTS = 25000;
constexpr int PATCH = 20;
constexpr int TS  = 8;               // tile edge
constexpr int TPD = GD / TS;         // 20
constexpr int NT  = TPD * TPD * TPD; // 8000 tiles
constexpr int CAP = 384;             // per-tile bucket capacity (mean ~81)
constexpr int PSTRIDE = 16;          // floats per gaussian struct
constexpr float L2E = 1.4426950408889634f;
}

// Param struct (16 floats, 4x float4), coefficients pre-scaled by log2(e),
// -0.5 folded; gather computes t in exp2 space directly:
//  P0 = (q00, q01, q02, q11)
//  P1 = (q12, q22, cvz, cvy)
//  P2 = (cvx, r0, r1, loPack)  loPack = loz|loy<<8|lox<<16|upz<<24
//  P3 = (upPack, v, 0, 0)      upPack = upy|upx<<8 ; v = 2^(2*q00) = e^-p00

__global__ __launch_bounds__(256) void prep_bin(
    const float* __restrict__ centers,
    const float* __restrict__ log_scales,
    const float* __restrict__ quats,
    const float* __restrict__ rho,
    float* __restrict__ params,
    int* __restrict__ counts,
    unsigned short* __restrict__ list)
{
    const int t = blockIdx.x * 256 + threadIdx.x;   // grid = NPTS*64 threads
    const int gid  = t >> 6;
    const int lane = t & 63;

    // ---- all 64 lanes compute the gaussian's params redundantly ----
    const float r0 = rho[gid * 2 + 0];
    const float r1 = rho[gid * 2 + 1];
    const float s0 = __expf(log_scales[gid * 3 + 0]);
    const float s1 = __expf(log_scales[gid * 3 + 1]);
    const float s2 = __expf(log_scales[gid * 3 + 2]);

    const float smax = fmaxf(s0, fmaxf(s1, s2));
    const float rad  = smax * 3.0f;          // RADIUS_FACTOR
    const float amp2 = r0 * r0 + r1 * r1;

    const float cvz = centers[gid * 3 + 0] * (float)(GD - 1);
    const float cvy = centers[gid * 3 + 1] * (float)(GH - 1);
    const float cvx = centers[gid * 3 + 2] * (float)(GW - 1);

    const int bz = (int)floorf(cvz - rad);
    const int by = (int)floorf(cvy - rad);
    const int bx = (int)floorf(cvx - rad);
    const int hz = (int)ceilf(cvz + rad);
    const int hy = (int)ceilf(cvy + rad);
    const int hx = (int)ceilf(cvx + rad);

    // reference mask: idx>=0 && idx<dim && idx<=hi, idx in [base, base+19]
    const int loz = max(bz, 0), upz = min(min(hz, GD - 1), bz + PATCH - 1);
    const int loy = max(by, 0), upy = min(min(hy, GH - 1), by + PATCH - 1);
    const int lox = max(bx, 0), upx = min(min(hx, GW - 1), bx + PATCH - 1);

    const bool valid = (amp2 >= 1e-12f) && (rad >= 1e-3f) &&
                       (upz >= loz) && (upy >= loy) && (upx >= lox);

    const float q0 = quats[gid * 4 + 0], q1 = quats[gid * 4 + 1];
    const float q2 = quats[gid * 4 + 2], q3 = quats[gid * 4 + 3];
    float qn = sqrtf(q0 * q0 + q1 * q1 + q2 * q2 + q3 * q3);
    qn = fmaxf(qn, 1e-6f);
    const float w = q0 / qn, x = q1 / qn, y = q2 / qn, z = q3 / qn;

    const float R00 = w * w + x * x - y * y - z * z;
    const float R01 = 2.f * (x * y - w * z);
    const float R02 = 2.f * (x * z + w * y);
    const float R10 = 2.f * (x * y + w * z);
    const float R11 = w * w - x * x + y * y - z * z;
    const float R12 = 2.f * (y * z - w * x);
    const float R20 = 2.f * (x * z - w * y);
    const float R21 = 2.f * (y * z + w * x);
    const float R22 = w * w - x * x - y * y + z * z;

    const float c0 = fmaxf(s0, 1e-4f); const float i0 = 1.f / (c0 * c0);
    const float c1 = fmaxf(s1, 1e-4f); const float i1 = 1.f / (c1 * c1);
    const float c2 = fmaxf(s2, 1e-4f); const float i2 = 1.f / (c2 * c2);

    const float p00 = R00 * R00 * i0 + R01 * R01 * i1 + R02 * R02 * i2;
    const float p01 = R00 * R10 * i0 + R01 * R11 * i1 + R02 * R12 * i2;
    const float p02 = R00 * R20 * i0 + R01 * R21 * i1 + R02 * R22 * i2;
    const float p11 = R10 * R10 * i0 + R11 * R11 * i1 + R12 * R12 * i2;
    const float p12 = R10 * R20 * i0 + R11 * R21 * i1 + R12 * R22 * i2;
    const float p22 = R20 * R20 * i0 + R21 * R21 * i1 + R22 * R22 * i2;

    const float q00s = -0.5f * L2E * p00;
    const float v    = __builtin_amdgcn_exp2f(2.f * q00s);  // e^-p00

    // invalid -> empty box (lo=255 > up=0): gather's masks reject all voxels
    const int zl = valid ? loz : 255, zu = valid ? upz : 0;
    const int yl = valid ? loy : 255, yu = valid ? upy : 0;
    const int xl = valid ? lox : 255, xu = valid ? upx : 0;
    const int loPack = zl | (yl << 8) | (xl << 16) | (zu << 24);
    const int upPack = yu | (xu << 8);

    if (lane == 0) {
        float4* P = reinterpret_cast<float4*>(params + (size_t)gid * PSTRIDE);
        P[0] = make_float4(q00s, -L2E * p01, -L2E * p02, -0.5f * L2E * p11);
        P[1] = make_float4(-L2E * p12, -0.5f * L2E * p22, cvz, cvy);
        P[2] = make_float4(cvx, r0, r1, __int_as_float(loPack));
        P[3] = make_float4(__int_as_float(upPack), v, 0.f, 0.f);
    }

    if (!valid) return;

    // ---- bin: one lane per candidate tile (box spans <=4 tiles per dim) ----
    const int tz0 = loz >> 3, tz1 = upz >> 3;
    const int ty0 = loy >> 3, ty1 = upy >> 3;
    const int tx0 = lox >> 3, tx1 = upx >> 3;
    const int tz = tz0 + (lane >> 4);
    const int ty = ty0 + ((lane >> 2) & 3);
    const int tx = tx0 + (lane & 3);
    if (tz > tz1 || ty > ty1 || tx > tx1) return;
    const int tile = (tz * TPD + ty) * TPD + tx;
    const int pos = atomicAdd(&counts[tile], 1);
    if (pos < CAP) list[(size_t)tile * CAP + pos] = (unsigned short)gid;
}

__global__ __launch_bounds__(256, 8) void gather(
    const float* __restrict__ params,
    const int* __restrict__ counts,
    const unsigned short* __restrict__ list,
    float2* __restrict__ out)
{
    // 4 INDEPENDENT waves per block, one tile each; no block barriers.
    const int wli  = threadIdx.x >> 6;
    const int lane = threadIdx.x & 63;
    const int tile = blockIdx.x * 4 + wli;          // grid = NT/4
    const int tz = tile / (TPD * TPD);
    const int rem = tile - tz * (TPD * TPD);
    const int ty = rem / TPD;
    const int tx = rem - ty * TPD;

    const int ly = lane >> 3, lx = lane & 7;
    const int iy = ty * TS + ly;
    const int ix = tx * TS + lx;
    const int z0 = tz * TS;
    const float fy = (float)iy, fx = (float)ix, fz = (float)z0;

    __shared__ float4 sP[4][64][4];   // per-wave 4 KB chunk; 16 KB/block

    int cnt = __builtin_amdgcn_readfirstlane(counts[tile]);
    if (cnt > CAP) cnt = CAP;
    const float4* p4 = reinterpret_cast<const float4*>(params);
    const unsigned short* tl = list + (size_t)tile * CAP;

    float ar[8], ai[8];
#pragma unroll
    for (int i = 0; i < 8; ++i) { ar[i] = 0.f; ai[i] = 0.f; }

    for (int b0 = 0; b0 < cnt; b0 += 64) {
        const int nb = min(64, cnt - b0);
        // per-wave staging: lane stages one full 64 B struct (R2 amortization)
        if (lane < nb) {
            const int g = tl[b0 + lane];
            const float4* src = p4 + (size_t)g * 4;
            sP[wli][lane][0] = src[0];
            sP[wli][lane][1] = src[1];
            sP[wli][lane][2] = src[2];
            sP[wli][lane][3] = src[3];
        }
        // same-wave ds_write -> ds_read: compiler-inserted lgkmcnt suffices
        for (int g = 0; g < nb; ++g) {
            const float4 Pa = sP[wli][g][0];
            const float4 Pb = sP[wli][g][1];
            const float4 Pc = sP[wli][g][2];
            const float2 Pd = *reinterpret_cast<const float2*>(&sP[wli][g][3]);
            // wave-uniform packed bounds -> SALU masking
            const int lo = __builtin_amdgcn_readfirstlane(__float_as_int(Pc.w));
            const int up = __builtin_amdgcn_readfirstlane(__float_as_int(Pd.x));
            const int loy_ = (lo >> 8) & 255, lox_ = (lo >> 16) & 255;
            const int upy_ = up & 255,        upx_ = (up >> 8) & 255;
            const int zl = (lo & 255) - z0;          // scalar, may be <0 or >7
            const int zu = ((lo >> 24) & 255) - z0;
            const bool yx = (iy >= loy_) & (iy <= upy_) &
                            (ix >= lox_) & (ix <= upx_);

            const float dy = fy - Pb.w;
            const float dx = fx - Pc.x;
            const float C = fmaf(dy, fmaf(Pa.w, dy, Pb.x * dx), Pb.y * dx * dx);
            const float B = fmaf(Pa.y, dy, Pa.z * dx);
            const float dz = fz - Pb.z;
            const float t0 = fmaf(dz, fmaf(Pa.x, dz, B), C);
            const float dt = fmaf(Pa.x, fmaf(2.f, dz, 1.f), B);
            float wgt = __builtin_amdgcn_exp2f(t0);  // weight at z0 (<=1)
            float u   = __builtin_amdgcn_exp2f(dt);  // ratio at z0
            const float v = Pd.y;                    // ratio of ratios
            const float r0m = yx ? Pc.y : 0.f;       // fold y/x reject
            const float r1m = yx ? Pc.z : 0.f;
#pragma unroll
            for (int i = 0; i < 8; ++i) {
                const float wm = (i >= zl && i <= zu) ? wgt : 0.f;
                ar[i] = fmaf(wm, r0m, ar[i]);
                ai[i] = fmaf(wm, r1m, ai[i]);
                wgt *= u;
                u *= v;
            }
        }
    }

#pragma unroll
    for (int i = 0; i < 8; ++i)
        out[((size_t)(z0 + i) * GH + iy) * GW + ix] = make_float2(ar[i], ai[i]);
}

extern "C" void kernel_launch(void* const* d_in, const int* in_sizes, int n_in,
                              void* d_out, int out_size, void* d_ws, size_t ws_size,
                              hipStream_t stream) {
    const float* centers    = (const float*)d_in[0];
    const float* log_scales = (const float*)d_in[1];
    const float* quats      = (const float*)d_in[2];
    const float* rho        = (const float*)d_in[3];

    // workspace: params (1.6 MB) | counts (32 KB) | list (6.1 MB)
    float* params = (float*)d_ws;
    int* counts = (int*)(params + (size_t)NPTS * PSTRIDE);
    unsigned short* list = (unsigned short*)(counts + NT);

    hipMemsetAsync(counts, 0, NT * sizeof(int), stream);
    prep_bin<<<(NPTS * 64) / 256, 256, 0, stream>>>(centers, log_scales, quats,
                                                    rho, params, counts, list);
    // gather writes every voxel exactly once -> no d_out memset needed
    gather<<<NT / 4, 256, 0, stream>>>(params, counts, list, (float2*)d_out);
}